// Round 11
// baseline (74.861 us; speedup 1.0000x reference)
//
#include <hip/hip_runtime.h>
#include <hip/hip_bf16.h>

// Problem constants (from setup_inputs): B=4, N=8192, M=8192, D=3, fp32.
constexpr int B = 4;
constexpr int N = 8192;
constexpr int M = 8192;

constexpr int QPW     = 64;            // queries per wave (2 B-fragments)
constexpr int WAVES   = 4;             // waves per block
constexpr int QB      = QPW * WAVES;   // 256 queries per block
constexpr int QTILES  = N / QB;        // 32
constexpr int PCHUNKS = 16;            // point split -> grid 2048 = 8 blocks/CU
constexpr int CHUNK   = M / PCHUNKS;   // 512 points per block
constexpr int PTILES  = CHUNK / 32;    // 16 A-tile loads, 32 mfmas per wave

typedef __bf16 bf16x8 __attribute__((ext_vector_type(8)));
typedef float  f32x16 __attribute__((ext_vector_type(16)));

union FragU { uint4 u; bf16x8 b; };

// fp32 -> bf16 bits, round-to-nearest-even (finite inputs only).
__device__ inline unsigned f2bf(float x) {
    unsigned u = __float_as_uint(x);
    return (u + 0x7FFFu + ((u >> 16) & 1u)) >> 16;
}
__device__ inline float bf2f(unsigned b) { return __uint_as_float(b << 16); }
__device__ inline unsigned pk(unsigned lo, unsigned hi) { return lo | (hi << 16); }

// ---------------------------------------------------------------------------
// K-slot packing (mfma_f32_32x32x16_bf16, A rows = points, B cols = queries):
//   k0..3 : A=(ph0,ph0,pl0,pl0)  B=(ah0,al0,ah0,al0)  -> (ph0+pl0)(ah0+al0)
//   k4..7 : dim 1   k8..11: dim 2   k12,13: A=(sh,sl) B=(1,1) -> ||p||^2
//   k14,15: 0         (p' = -2p, everything split bf16 hi/lo)
// acc[row=point][col=query] = -2 a.p + ||p||^2  (validated R7/R8: absmax
// 7.8e-3 vs 6.75e-2 threshold).
// A-frag layout: A[m=lane&31][k=(lane>>5)*8+j] -> two 16B halves per point.
// This is the round-8 structure (best measured: 66.0 us) with one change:
// 4 A-tile loads batched per loop iteration for deeper VMEM pipelining.
// R9 (LDS fusion) and R10 (quad-B, grid 1024) both regressed — do not revisit.
// ---------------------------------------------------------------------------

// Prep: pack each point's two A-fragment halves into wtab (32 B/point, 1 MB)
// AND initialize out to 0x7F7F7F7F (3.39e38f; uint order == float order for
// non-negative floats, so atomicMin(uint) implements float min). B*M == B*N.
__global__ __launch_bounds__(256) void prep_kernel(const float* __restrict__ point,
                                                   uint4* __restrict__ wtab,
                                                   unsigned int* __restrict__ out) {
    int i = blockIdx.x * 256 + threadIdx.x;   // 0 .. B*M-1
    if (i >= B * M) return;
    const float p0 = point[3 * i + 0];
    const float p1 = point[3 * i + 1];
    const float p2 = point[3 * i + 2];
    const float v0 = -2.0f * p0, v1 = -2.0f * p1, v2 = -2.0f * p2;
    const unsigned h0 = f2bf(v0), l0 = f2bf(v0 - bf2f(h0));
    const unsigned h1 = f2bf(v1), l1 = f2bf(v1 - bf2f(h1));
    const unsigned h2 = f2bf(v2), l2 = f2bf(v2 - bf2f(h2));
    const float s = fmaf(p0, p0, fmaf(p1, p1, p2 * p2));
    const unsigned sh = f2bf(s), sl = f2bf(s - bf2f(sh));
    uint4 f0, f1;
    f0.x = pk(h0, h0); f0.y = pk(l0, l0); f0.z = pk(h1, h1); f0.w = pk(l1, l1); // k0..7
    f1.x = pk(h2, h2); f1.y = pk(l2, l2); f1.z = pk(sh, sl); f1.w = 0;          // k8..15
    wtab[2 * i + 0] = f0;
    wtab[2 * i + 1] = f1;
    out[i] = 0x7F7F7F7Fu;
}

// Build the B fragment for query index q (this lane's column).
__device__ inline FragU make_bfrag(const float* __restrict__ input,
                                   int b, int q, int h, float& sq_a) {
    const float* a = input + ((size_t)b * N + q) * 3;
    const float a0 = a[0], a1 = a[1], a2 = a[2];
    sq_a = fmaf(a0, a0, fmaf(a1, a1, a2 * a2));
    const unsigned ah0 = f2bf(a0), al0 = f2bf(a0 - bf2f(ah0));
    const unsigned ah1 = f2bf(a1), al1 = f2bf(a1 - bf2f(ah1));
    const unsigned ah2 = f2bf(a2), al2 = f2bf(a2 - bf2f(ah2));
    FragU bq;
    const unsigned dA = h ? pk(ah2, al2) : pk(ah0, al0);
    const unsigned dB = h ? 0x3F803F80u  : pk(ah1, al1);   // (1,1) bf16 | dim1
    bq.u.x = dA;
    bq.u.y = dA;
    bq.u.z = dB;
    bq.u.w = h ? 0u : dB;
    return bq;
}

// Main: one wave = 64 queries (2 B frags) vs its 512-point chunk.
// Per iteration: 4 A-tile loads batched (deep VMEM pipeline), then 8 mfmas
// + 64 v_min3 (8/mfma, pairing A-tiles per B-frag).
__global__ __launch_bounds__(256, 3) void main_kernel(const float* __restrict__ input,
                                                      const uint4* __restrict__ wtab,
                                                      unsigned int* __restrict__ out) {
    const int bid    = blockIdx.x;
    const int pchunk = bid % PCHUNKS;
    const int qtile  = (bid / PCHUNKS) % QTILES;
    const int b      = bid / (PCHUNKS * QTILES);
    const int tid    = threadIdx.x;
    const int wave   = tid >> 6;
    const int lane   = tid & 63;
    const int col    = lane & 31;          // A: point row in tile; B: query col
    const int h      = lane >> 5;          // k-half

    const int q0 = qtile * QB + wave * QPW + col;        // first query set
    const int q1 = q0 + 32;                              // second query set
    float sq_a0, sq_a1;
    const FragU b0 = make_bfrag(input, b, q0, h, sq_a0);
    const FragU b1 = make_bfrag(input, b, q1, h, sq_a1);

    const uint4* __restrict__ wp =
        wtab + ((size_t)b * M + (size_t)pchunk * CHUNK) * 2;

    f32x16 cz, rmin0, rmin1;
#pragma unroll
    for (int i = 0; i < 16; ++i) { cz[i] = 0.0f; rmin0[i] = 1e30f; rmin1[i] = 1e30f; }

    for (int t = 0; t < PTILES; t += 4) {
        FragU fa0, fa1, fa2, fa3;
        fa0.u = wp[(((t + 0) * 32 + col) << 1) + h];
        fa1.u = wp[(((t + 1) * 32 + col) << 1) + h];
        fa2.u = wp[(((t + 2) * 32 + col) << 1) + h];
        fa3.u = wp[(((t + 3) * 32 + col) << 1) + h];

        f32x16 acc00 = __builtin_amdgcn_mfma_f32_32x32x16_bf16(fa0.b, b0.b, cz, 0, 0, 0);
        f32x16 acc10 = __builtin_amdgcn_mfma_f32_32x32x16_bf16(fa1.b, b0.b, cz, 0, 0, 0);
        f32x16 acc01 = __builtin_amdgcn_mfma_f32_32x32x16_bf16(fa0.b, b1.b, cz, 0, 0, 0);
        f32x16 acc11 = __builtin_amdgcn_mfma_f32_32x32x16_bf16(fa1.b, b1.b, cz, 0, 0, 0);
#pragma unroll
        for (int i = 0; i < 16; ++i) {
            rmin0[i] = fminf(rmin0[i], fminf(acc00[i], acc10[i]));   // v_min3_f32
            rmin1[i] = fminf(rmin1[i], fminf(acc01[i], acc11[i]));   // v_min3_f32
        }

        f32x16 acc20 = __builtin_amdgcn_mfma_f32_32x32x16_bf16(fa2.b, b0.b, cz, 0, 0, 0);
        f32x16 acc30 = __builtin_amdgcn_mfma_f32_32x32x16_bf16(fa3.b, b0.b, cz, 0, 0, 0);
        f32x16 acc21 = __builtin_amdgcn_mfma_f32_32x32x16_bf16(fa2.b, b1.b, cz, 0, 0, 0);
        f32x16 acc31 = __builtin_amdgcn_mfma_f32_32x32x16_bf16(fa3.b, b1.b, cz, 0, 0, 0);
#pragma unroll
        for (int i = 0; i < 16; ++i) {
            rmin0[i] = fminf(rmin0[i], fminf(acc20[i], acc30[i]));   // v_min3_f32
            rmin1[i] = fminf(rmin1[i], fminf(acc21[i], acc31[i]));   // v_min3_f32
        }
    }

    // Epilogue: in-lane fold (16 rows) + cross-half shuffle (other 16 rows).
    float m0 = rmin0[0], m1 = rmin1[0];
#pragma unroll
    for (int i = 1; i < 16; ++i) { m0 = fminf(m0, rmin0[i]); m1 = fminf(m1, rmin1[i]); }
    m0 = fminf(m0, __shfl_xor(m0, 32, 64));
    m1 = fminf(m1, __shfl_xor(m1, 32, 64));

    if (lane < 32) {
        atomicMin(&out[(size_t)b * N + q0], __float_as_uint(fmaxf(m0 + sq_a0, 0.0f)));
        atomicMin(&out[(size_t)b * N + q1], __float_as_uint(fmaxf(m1 + sq_a1, 0.0f)));
    }
}

extern "C" void kernel_launch(void* const* d_in, const int* in_sizes, int n_in,
                              void* d_out, int out_size, void* d_ws, size_t ws_size,
                              hipStream_t stream) {
    const float* input = (const float*)d_in[0];   // [B, N, 3] fp32
    const float* point = (const float*)d_in[1];   // [B, M, 3] fp32
    unsigned int* out  = (unsigned int*)d_out;    // [B, N] fp32 viewed as uint

    uint4* wtab = (uint4*)d_ws;                   // 1 MB packed A-fragment table

    const int prep_grid = (B * M + 255) / 256;        // 128 blocks
    const int main_grid = B * QTILES * PCHUNKS;       // 2048 blocks

    prep_kernel<<<prep_grid, 256, 0, stream>>>(point, wtab, out);
    main_kernel<<<main_grid, 256, 0, stream>>>(input, wtab, out);
}

// Round 12
// 66.989 us; speedup vs baseline: 1.1175x; 1.1175x over previous
//
#include <hip/hip_runtime.h>
#include <hip/hip_bf16.h>

// Problem constants (from setup_inputs): B=4, N=8192, M=8192, D=3, fp32.
constexpr int B = 4;
constexpr int N = 8192;
constexpr int M = 8192;

constexpr int QPW     = 64;            // queries per wave (2 B-fragments)
constexpr int WAVES   = 4;             // waves per block
constexpr int QB      = QPW * WAVES;   // 256 queries per block
constexpr int QTILES  = N / QB;        // 32
constexpr int PCHUNKS = 16;            // point split -> grid 2048 = 8 blocks/CU
constexpr int CHUNK   = M / PCHUNKS;   // 512 points per block
constexpr int PTILES  = CHUNK / 32;    // 16 A-tile loads, 32 mfmas per wave

typedef __bf16 bf16x8 __attribute__((ext_vector_type(8)));
typedef float  f32x16 __attribute__((ext_vector_type(16)));

union FragU { uint4 u; bf16x8 b; };

// fp32 -> bf16 bits, round-to-nearest-even (finite inputs only).
__device__ __host__ inline unsigned f2bf(float x) {
    unsigned u = __float_as_uint(x);
    return (u + 0x7FFFu + ((u >> 16) & 1u)) >> 16;
}
__device__ inline float bf2f(unsigned b) { return __uint_as_float(b << 16); }
__device__ inline unsigned pk(unsigned lo, unsigned hi) { return lo | (hi << 16); }

// ---------------------------------------------------------------------------
// EXACT round-8 source, re-benched for reproducibility: R8 measured 66.0 us
// while R7/R9/R10/R11 all land 73-75 us despite structural diversity. This
// run decides whether 66.0 was real (R8's exact schedule is special) or
// favorable noise (plateau ~74, kernel already at floor since R7).
//
// K-slot packing (mfma_f32_32x32x16_bf16, A rows = points, B cols = queries):
//   k0..3 : A=(ph0,ph0,pl0,pl0)  B=(ah0,al0,ah0,al0)  -> (ph0+pl0)(ah0+al0)
//   k4..7 : dim 1   k8..11: dim 2   k12,13: A=(sh,sl) B=(1,1) -> ||p||^2
//   k14,15: 0         (p' = -2p, everything split bf16 hi/lo)
// acc[row=point][col=query] = -2 a.p + ||p||^2   (validated: absmax 7.8e-3
// vs 6.75e-2 threshold).
// A-frag layout: A[m=lane&31][k=(lane>>5)*8+j] -> two 16B halves per point.
// ---------------------------------------------------------------------------

// Prep: pack each point's two A-fragment halves into wtab (32 B/point, 1 MB)
// AND initialize out to 0x7F7F7F7F (3.39e38f; uint order == float order for
// non-negative floats, so atomicMin(uint) implements float min). B*M == B*N.
__global__ __launch_bounds__(256) void prep_kernel(const float* __restrict__ point,
                                                   uint4* __restrict__ wtab,
                                                   unsigned int* __restrict__ out) {
    int i = blockIdx.x * 256 + threadIdx.x;   // 0 .. B*M-1
    if (i >= B * M) return;
    const float p0 = point[3 * i + 0];
    const float p1 = point[3 * i + 1];
    const float p2 = point[3 * i + 2];
    const float v0 = -2.0f * p0, v1 = -2.0f * p1, v2 = -2.0f * p2;
    const unsigned h0 = f2bf(v0), l0 = f2bf(v0 - bf2f(h0));
    const unsigned h1 = f2bf(v1), l1 = f2bf(v1 - bf2f(h1));
    const unsigned h2 = f2bf(v2), l2 = f2bf(v2 - bf2f(h2));
    const float s = fmaf(p0, p0, fmaf(p1, p1, p2 * p2));
    const unsigned sh = f2bf(s), sl = f2bf(s - bf2f(sh));
    uint4 f0, f1;
    f0.x = pk(h0, h0); f0.y = pk(l0, l0); f0.z = pk(h1, h1); f0.w = pk(l1, l1); // k0..7
    f1.x = pk(h2, h2); f1.y = pk(l2, l2); f1.z = pk(sh, sl); f1.w = 0;          // k8..15
    wtab[2 * i + 0] = f0;
    wtab[2 * i + 1] = f1;
    out[i] = 0x7F7F7F7Fu;
}

// Build the B fragment for query index q (this lane's column).
__device__ inline FragU make_bfrag(const float* __restrict__ input,
                                   int b, int q, int h, float& sq_a) {
    const float* a = input + ((size_t)b * N + q) * 3;
    const float a0 = a[0], a1 = a[1], a2 = a[2];
    sq_a = fmaf(a0, a0, fmaf(a1, a1, a2 * a2));
    const unsigned ah0 = f2bf(a0), al0 = f2bf(a0 - bf2f(ah0));
    const unsigned ah1 = f2bf(a1), al1 = f2bf(a1 - bf2f(ah1));
    const unsigned ah2 = f2bf(a2), al2 = f2bf(a2 - bf2f(ah2));
    FragU bq;
    const unsigned dA = h ? pk(ah2, al2) : pk(ah0, al0);
    const unsigned dB = h ? 0x3F803F80u  : pk(ah1, al1);   // (1,1) bf16 | dim1
    bq.u.x = dA;
    bq.u.y = dA;
    bq.u.z = dB;
    bq.u.w = h ? 0u : dB;
    return bq;
}

// Main: one wave = 64 queries (2 B frags) vs its 512-point chunk.
// Per 2 A-tile loads: 4 mfmas + 32 v_min3 (8/mfma, optimal). Each A load
// feeds 2 mfmas.
__global__ __launch_bounds__(256, 3) void main_kernel(const float* __restrict__ input,
                                                      const uint4* __restrict__ wtab,
                                                      unsigned int* __restrict__ out) {
    const int bid    = blockIdx.x;
    const int pchunk = bid % PCHUNKS;
    const int qtile  = (bid / PCHUNKS) % QTILES;
    const int b      = bid / (PCHUNKS * QTILES);
    const int tid    = threadIdx.x;
    const int wave   = tid >> 6;
    const int lane   = tid & 63;
    const int col    = lane & 31;          // A: point row in tile; B: query col
    const int h      = lane >> 5;          // k-half

    const int q0 = qtile * QB + wave * QPW + col;        // first query set
    const int q1 = q0 + 32;                              // second query set
    float sq_a0, sq_a1;
    const FragU b0 = make_bfrag(input, b, q0, h, sq_a0);
    const FragU b1 = make_bfrag(input, b, q1, h, sq_a1);

    const uint4* __restrict__ wp =
        wtab + ((size_t)b * M + (size_t)pchunk * CHUNK) * 2;

    f32x16 cz, rmin0, rmin1;
#pragma unroll
    for (int i = 0; i < 16; ++i) { cz[i] = 0.0f; rmin0[i] = 1e30f; rmin1[i] = 1e30f; }

    for (int t = 0; t < PTILES; t += 2) {
        FragU fa0, fa1;
        fa0.u = wp[((t * 32 + col) << 1) + h];
        fa1.u = wp[(((t + 1) * 32 + col) << 1) + h];
        f32x16 acc00 = __builtin_amdgcn_mfma_f32_32x32x16_bf16(fa0.b, b0.b, cz, 0, 0, 0);
        f32x16 acc01 = __builtin_amdgcn_mfma_f32_32x32x16_bf16(fa0.b, b1.b, cz, 0, 0, 0);
        f32x16 acc10 = __builtin_amdgcn_mfma_f32_32x32x16_bf16(fa1.b, b0.b, cz, 0, 0, 0);
        f32x16 acc11 = __builtin_amdgcn_mfma_f32_32x32x16_bf16(fa1.b, b1.b, cz, 0, 0, 0);
#pragma unroll
        for (int i = 0; i < 16; ++i) {
            rmin0[i] = fminf(rmin0[i], fminf(acc00[i], acc10[i]));   // v_min3_f32
            rmin1[i] = fminf(rmin1[i], fminf(acc01[i], acc11[i]));   // v_min3_f32
        }
    }

    // Epilogue: in-lane fold (16 rows) + cross-half shuffle (other 16 rows).
    float m0 = rmin0[0], m1 = rmin1[0];
#pragma unroll
    for (int i = 1; i < 16; ++i) { m0 = fminf(m0, rmin0[i]); m1 = fminf(m1, rmin1[i]); }
    m0 = fminf(m0, __shfl_xor(m0, 32, 64));
    m1 = fminf(m1, __shfl_xor(m1, 32, 64));

    if (lane < 32) {
        atomicMin(&out[(size_t)b * N + q0], __float_as_uint(fmaxf(m0 + sq_a0, 0.0f)));
        atomicMin(&out[(size_t)b * N + q1], __float_as_uint(fmaxf(m1 + sq_a1, 0.0f)));
    }
}

extern "C" void kernel_launch(void* const* d_in, const int* in_sizes, int n_in,
                              void* d_out, int out_size, void* d_ws, size_t ws_size,
                              hipStream_t stream) {
    const float* input = (const float*)d_in[0];   // [B, N, 3] fp32
    const float* point = (const float*)d_in[1];   // [B, M, 3] fp32
    unsigned int* out  = (unsigned int*)d_out;    // [B, N] fp32 viewed as uint

    uint4* wtab = (uint4*)d_ws;                   // 1 MB packed A-fragment table

    const int prep_grid = (B * M + 255) / 256;        // 128 blocks
    const int main_grid = B * QTILES * PCHUNKS;       // 2048 blocks

    prep_kernel<<<prep_grid, 256, 0, stream>>>(point, wtab, out);
    main_kernel<<<main_grid, 256, 0, stream>>>(input, wtab, out);
}

// Round 13
// 66.057 us; speedup vs baseline: 1.1333x; 1.0141x over previous
//
#include <hip/hip_runtime.h>
#include <hip/hip_bf16.h>

// Problem constants (from setup_inputs): B=4, N=8192, M=8192, D=3, fp32.
constexpr int B = 4;
constexpr int N = 8192;
constexpr int M = 8192;

constexpr int QPW     = 64;            // queries per wave (2 B-fragments)
constexpr int WAVES   = 4;             // waves per block
constexpr int QB      = QPW * WAVES;   // 256 queries per block
constexpr int QTILES  = N / QB;        // 32
constexpr int PCHUNKS = 16;            // point split -> grid 2048 = 8 blocks/CU
constexpr int CHUNK   = M / PCHUNKS;   // 512 points per block
constexpr int PTILES  = CHUNK / 32;    // 16 A-tile loads, 32 mfmas per wave

typedef __bf16 bf16x8 __attribute__((ext_vector_type(8)));
typedef float  f32x16 __attribute__((ext_vector_type(16)));

union FragU { uint4 u; bf16x8 b; };

// fp32 -> bf16 bits, round-to-nearest-even (finite inputs only).
__device__ __host__ inline unsigned f2bf(float x) {
    unsigned u = __float_as_uint(x);
    return (u + 0x7FFFu + ((u >> 16) & 1u)) >> 16;
}
__device__ inline float bf2f(unsigned b) { return __uint_as_float(b << 16); }
__device__ inline unsigned pk(unsigned lo, unsigned hi) { return lo | (hi << 16); }

// ---------------------------------------------------------------------------
// Round-8 structure (reproduced twice: 66.0 / 67.0 us; noise ~±1 us).
// SINGLE change this round: __launch_bounds__(256,3) -> (256,4) on main
// (12 -> 16 waves/CU if the body fits a 128-VGPR cap without spilling).
// R9 (LDS fusion), R10 (quad-B), R11 (batch-4 loads) all regressed to ~74.
//
// K-slot packing (mfma_f32_32x32x16_bf16, A rows = points, B cols = queries):
//   k0..3 : A=(ph0,ph0,pl0,pl0)  B=(ah0,al0,ah0,al0)  -> (ph0+pl0)(ah0+al0)
//   k4..7 : dim 1   k8..11: dim 2   k12,13: A=(sh,sl) B=(1,1) -> ||p||^2
//   k14,15: 0         (p' = -2p, everything split bf16 hi/lo)
// acc[row=point][col=query] = -2 a.p + ||p||^2   (validated: absmax 7.8e-3
// vs 6.75e-2 threshold).
// A-frag layout: A[m=lane&31][k=(lane>>5)*8+j] -> two 16B halves per point.
// ---------------------------------------------------------------------------

// Prep: pack each point's two A-fragment halves into wtab (32 B/point, 1 MB)
// AND initialize out to 0x7F7F7F7F (3.39e38f; uint order == float order for
// non-negative floats, so atomicMin(uint) implements float min). B*M == B*N.
__global__ __launch_bounds__(256) void prep_kernel(const float* __restrict__ point,
                                                   uint4* __restrict__ wtab,
                                                   unsigned int* __restrict__ out) {
    int i = blockIdx.x * 256 + threadIdx.x;   // 0 .. B*M-1
    if (i >= B * M) return;
    const float p0 = point[3 * i + 0];
    const float p1 = point[3 * i + 1];
    const float p2 = point[3 * i + 2];
    const float v0 = -2.0f * p0, v1 = -2.0f * p1, v2 = -2.0f * p2;
    const unsigned h0 = f2bf(v0), l0 = f2bf(v0 - bf2f(h0));
    const unsigned h1 = f2bf(v1), l1 = f2bf(v1 - bf2f(h1));
    const unsigned h2 = f2bf(v2), l2 = f2bf(v2 - bf2f(h2));
    const float s = fmaf(p0, p0, fmaf(p1, p1, p2 * p2));
    const unsigned sh = f2bf(s), sl = f2bf(s - bf2f(sh));
    uint4 f0, f1;
    f0.x = pk(h0, h0); f0.y = pk(l0, l0); f0.z = pk(h1, h1); f0.w = pk(l1, l1); // k0..7
    f1.x = pk(h2, h2); f1.y = pk(l2, l2); f1.z = pk(sh, sl); f1.w = 0;          // k8..15
    wtab[2 * i + 0] = f0;
    wtab[2 * i + 1] = f1;
    out[i] = 0x7F7F7F7Fu;
}

// Build the B fragment for query index q (this lane's column).
__device__ inline FragU make_bfrag(const float* __restrict__ input,
                                   int b, int q, int h, float& sq_a) {
    const float* a = input + ((size_t)b * N + q) * 3;
    const float a0 = a[0], a1 = a[1], a2 = a[2];
    sq_a = fmaf(a0, a0, fmaf(a1, a1, a2 * a2));
    const unsigned ah0 = f2bf(a0), al0 = f2bf(a0 - bf2f(ah0));
    const unsigned ah1 = f2bf(a1), al1 = f2bf(a1 - bf2f(ah1));
    const unsigned ah2 = f2bf(a2), al2 = f2bf(a2 - bf2f(ah2));
    FragU bq;
    const unsigned dA = h ? pk(ah2, al2) : pk(ah0, al0);
    const unsigned dB = h ? 0x3F803F80u  : pk(ah1, al1);   // (1,1) bf16 | dim1
    bq.u.x = dA;
    bq.u.y = dA;
    bq.u.z = dB;
    bq.u.w = h ? 0u : dB;
    return bq;
}

// Main: one wave = 64 queries (2 B frags) vs its 512-point chunk.
// Per 2 A-tile loads: 4 mfmas + 32 v_min3 (8/mfma). Each A load feeds 2 mfmas.
__global__ __launch_bounds__(256, 4) void main_kernel(const float* __restrict__ input,
                                                      const uint4* __restrict__ wtab,
                                                      unsigned int* __restrict__ out) {
    const int bid    = blockIdx.x;
    const int pchunk = bid % PCHUNKS;
    const int qtile  = (bid / PCHUNKS) % QTILES;
    const int b      = bid / (PCHUNKS * QTILES);
    const int tid    = threadIdx.x;
    const int wave   = tid >> 6;
    const int lane   = tid & 63;
    const int col    = lane & 31;          // A: point row in tile; B: query col
    const int h      = lane >> 5;          // k-half

    const int q0 = qtile * QB + wave * QPW + col;        // first query set
    const int q1 = q0 + 32;                              // second query set
    float sq_a0, sq_a1;
    const FragU b0 = make_bfrag(input, b, q0, h, sq_a0);
    const FragU b1 = make_bfrag(input, b, q1, h, sq_a1);

    const uint4* __restrict__ wp =
        wtab + ((size_t)b * M + (size_t)pchunk * CHUNK) * 2;

    f32x16 cz, rmin0, rmin1;
#pragma unroll
    for (int i = 0; i < 16; ++i) { cz[i] = 0.0f; rmin0[i] = 1e30f; rmin1[i] = 1e30f; }

    for (int t = 0; t < PTILES; t += 2) {
        FragU fa0, fa1;
        fa0.u = wp[((t * 32 + col) << 1) + h];
        fa1.u = wp[(((t + 1) * 32 + col) << 1) + h];
        f32x16 acc00 = __builtin_amdgcn_mfma_f32_32x32x16_bf16(fa0.b, b0.b, cz, 0, 0, 0);
        f32x16 acc01 = __builtin_amdgcn_mfma_f32_32x32x16_bf16(fa0.b, b1.b, cz, 0, 0, 0);
        f32x16 acc10 = __builtin_amdgcn_mfma_f32_32x32x16_bf16(fa1.b, b0.b, cz, 0, 0, 0);
        f32x16 acc11 = __builtin_amdgcn_mfma_f32_32x32x16_bf16(fa1.b, b1.b, cz, 0, 0, 0);
#pragma unroll
        for (int i = 0; i < 16; ++i) {
            rmin0[i] = fminf(rmin0[i], fminf(acc00[i], acc10[i]));   // v_min3_f32
            rmin1[i] = fminf(rmin1[i], fminf(acc01[i], acc11[i]));   // v_min3_f32
        }
    }

    // Epilogue: in-lane fold (16 rows) + cross-half shuffle (other 16 rows).
    float m0 = rmin0[0], m1 = rmin1[0];
#pragma unroll
    for (int i = 1; i < 16; ++i) { m0 = fminf(m0, rmin0[i]); m1 = fminf(m1, rmin1[i]); }
    m0 = fminf(m0, __shfl_xor(m0, 32, 64));
    m1 = fminf(m1, __shfl_xor(m1, 32, 64));

    if (lane < 32) {
        atomicMin(&out[(size_t)b * N + q0], __float_as_uint(fmaxf(m0 + sq_a0, 0.0f)));
        atomicMin(&out[(size_t)b * N + q1], __float_as_uint(fmaxf(m1 + sq_a1, 0.0f)));
    }
}

extern "C" void kernel_launch(void* const* d_in, const int* in_sizes, int n_in,
                              void* d_out, int out_size, void* d_ws, size_t ws_size,
                              hipStream_t stream) {
    const float* input = (const float*)d_in[0];   // [B, N, 3] fp32
    const float* point = (const float*)d_in[1];   // [B, M, 3] fp32
    unsigned int* out  = (unsigned int*)d_out;    // [B, N] fp32 viewed as uint

    uint4* wtab = (uint4*)d_ws;                   // 1 MB packed A-fragment table

    const int prep_grid = (B * M + 255) / 256;        // 128 blocks
    const int main_grid = B * QTILES * PCHUNKS;       // 2048 blocks

    prep_kernel<<<prep_grid, 256, 0, stream>>>(point, wtab, out);
    main_kernel<<<main_grid, 256, 0, stream>>>(input, wtab, out);
}